// Round 1
// baseline (328.660 us; speedup 1.0000x reference)
//
#include <hip/hip_runtime.h>

#define HDIM 128
#define XDIM 66
#define EDIM 6
#define NGRAPHS 256
#define LN_EPS 1e-5f

// ---------------- K1: degree histograms of edge_index ----------------
__global__ void k_hist(const int* __restrict__ ei, float* __restrict__ c_src,
                       float* __restrict__ c_dst, int E) {
    int e = blockIdx.x * blockDim.x + threadIdx.x;
    if (e < E) {
        atomicAdd(&c_src[ei[e]], 1.0f);
        atomicAdd(&c_dst[ei[E + e]], 1.0f);
    }
}

// ---------------- K2: column-sum of edge_attr (E,6) ----------------
__global__ __launch_bounds__(256) void k_edgesum(const float* __restrict__ ea,
                                                 float* __restrict__ sum_attr, int E) {
    int nchunk = E >> 1;  // 12 floats (2 edges) per chunk; E is even
    float a0 = 0, a1 = 0, a2 = 0, a3 = 0, a4 = 0, a5 = 0;
    for (int c = blockIdx.x * blockDim.x + threadIdx.x; c < nchunk;
         c += gridDim.x * blockDim.x) {
        const float4* p = (const float4*)(ea + (size_t)c * 12);
        float4 v0 = p[0], v1 = p[1], v2 = p[2];
        a0 += v0.x + v1.z;  a1 += v0.y + v1.w;  a2 += v0.z + v2.x;
        a3 += v0.w + v2.y;  a4 += v1.x + v2.z;  a5 += v1.y + v2.w;
    }
#pragma unroll
    for (int m = 32; m; m >>= 1) {
        a0 += __shfl_xor(a0, m); a1 += __shfl_xor(a1, m); a2 += __shfl_xor(a2, m);
        a3 += __shfl_xor(a3, m); a4 += __shfl_xor(a4, m); a5 += __shfl_xor(a5, m);
    }
    __shared__ float sbuf[4][6];
    int lane = threadIdx.x & 63, w = threadIdx.x >> 6;
    if (lane == 0) {
        sbuf[w][0] = a0; sbuf[w][1] = a1; sbuf[w][2] = a2;
        sbuf[w][3] = a3; sbuf[w][4] = a4; sbuf[w][5] = a5;
    }
    __syncthreads();
    if (threadIdx.x < 6) {
        float s = sbuf[0][threadIdx.x] + sbuf[1][threadIdx.x] +
                  sbuf[2][threadIdx.x] + sbuf[3][threadIdx.x];
        atomicAdd(&sum_attr[threadIdx.x], s);
    }
}

// ---------------- K3: h = x @ w_node + b_node, + weighted sums for layer 0 ----------------
__global__ __launch_bounds__(256) void k_node(const float* __restrict__ x,
        const float* __restrict__ w_node, const float* __restrict__ b_node,
        const float* __restrict__ c_src, const float* __restrict__ c_dst,
        float* __restrict__ h, float* __restrict__ partials, int N) {
    int t = threadIdx.x;
    int col = t & 127, par = t >> 7;
    float w[XDIM];
#pragma unroll
    for (int k = 0; k < XDIM; ++k) w[k] = w_node[k * HDIM + col];
    float bias = b_node[col];
    float accS = 0.f, accD = 0.f;
    int P = (N + 1) >> 1;
    for (int pr = blockIdx.x; pr < P; pr += gridDim.x) {
        int n = 2 * pr + par;
        if (n >= N) continue;
        int nu = __builtin_amdgcn_readfirstlane(n);   // wave-uniform -> scalar loads
        const float* xr = x + (size_t)nu * XDIM;
        float acc = bias;
#pragma unroll
        for (int k = 0; k < XDIM; ++k) acc = fmaf(xr[k], w[k], acc);
        h[(size_t)n * HDIM + col] = acc;
        accS = fmaf(c_src[nu], acc, accS);
        accD = fmaf(c_dst[nu], acc, accD);
    }
    float* row = partials + (size_t)blockIdx.x * 512;
    row[t] = accS;
    row[256 + t] = accD;
}

// ---------------- K4a: reduce per-block partials -> s_cat_g[512] ----------------
__global__ __launch_bounds__(256) void k_red(const float* __restrict__ partials,
                                             float* __restrict__ s_cat_g, int nb) {
    int b0 = blockIdx.x * 32;
    int b1 = min(nb, b0 + 32);
    int t = threadIdx.x;
    float s0 = 0.f, s1 = 0.f;
    for (int b = b0; b < b1; ++b) {
        const float* row = partials + (size_t)b * 512;
        s0 += row[t];
        s1 += row[t + 256];
    }
    atomicAdd(&s_cat_g[t], s0);
    atomicAdd(&s_cat_g[t + 256], s1);
}

// ---------------- K4b: mean_msg = (s_cat @ W)/E + mp_b ; zero s_cat_g ----------------
__global__ __launch_bounds__(256) void k_mm(float* __restrict__ s_cat_g,
        const float* __restrict__ sum_attr, const float* __restrict__ w_edge,
        const float* __restrict__ b_edge, const float* __restrict__ W,
        const float* __restrict__ mpb, float* __restrict__ mean_msg, int E) {
    __shared__ float sc[384];
    __shared__ float mred[256];
    int t = threadIdx.x;
    if (t < 128) {
        sc[t]       = s_cat_g[t]       + s_cat_g[t + 128];   // s_src (parity combine)
        sc[128 + t] = s_cat_g[256 + t] + s_cat_g[384 + t];   // s_dst
        float se = (float)E * b_edge[t];
#pragma unroll
        for (int k = 0; k < EDIM; ++k) se = fmaf(sum_attr[k], w_edge[k * HDIM + t], se);
        sc[256 + t] = se;                                    // sum over edges of ef
    }
    __syncthreads();
    // safe now: all reads of s_cat_g done -> zero it for next layer's atomics
    s_cat_g[t] = 0.f;
    s_cat_g[t + 256] = 0.f;
    int col = t & 127, half = t >> 7;
    float acc = 0.f;
#pragma unroll 8
    for (int r = half * 192; r < half * 192 + 192; ++r)
        acc = fmaf(sc[r], W[r * HDIM + col], acc);
    mred[t] = acc;
    __syncthreads();
    if (t < 128)
        mean_msg[t] = (mred[t] + mred[t + 128]) * (1.0f / (float)E) + mpb[t];
}

// ---------------- K5: h = relu(LN(h + mean_msg)); accumulate next-layer sums or pooling ----------------
template <int LAST>
__global__ __launch_bounds__(256) void k_update(
        float* __restrict__ h, const float* __restrict__ mean_msg,
        const float* __restrict__ ln_g, const float* __restrict__ ln_b,
        const float* __restrict__ c_src, const float* __restrict__ c_dst,
        const int* __restrict__ batch, float* __restrict__ partials,
        float* __restrict__ pooled, int N, int cpb) {
    int t = threadIdx.x;
    int lane = t & 63, w = t >> 6;
    int c0 = lane * 2;
    float2 mm = *(const float2*)(mean_msg + c0);
    float2 g  = *(const float2*)(ln_g + c0);
    float2 bb = *(const float2*)(ln_b + c0);
    int start = blockIdx.x * cpb;
    int end = min(N, start + cpb);
    int spw = (cpb + 3) >> 2;
    int nws = start + w * spw;
    int nwe = min(end, nws + spw);
    float2 accS = {0.f, 0.f}, accD = {0.f, 0.f}, accP = {0.f, 0.f};
    int cur_g = -1;
    for (int n = nws; n < nwe; ++n) {
        float2 v = *(const float2*)(h + (size_t)n * HDIM + c0);
        v.x += mm.x; v.y += mm.y;
        float s = v.x + v.y;
#pragma unroll
        for (int m = 32; m; m >>= 1) s += __shfl_xor(s, m);
        float mu = s * (1.0f / HDIM);
        float dx = v.x - mu, dy = v.y - mu;
        float q = dx * dx + dy * dy;
#pragma unroll
        for (int m = 32; m; m >>= 1) q += __shfl_xor(q, m);
        float rs = rsqrtf(q * (1.0f / HDIM) + LN_EPS);
        float2 o;
        o.x = fmaxf(0.f, fmaf(dx * rs, g.x, bb.x));
        o.y = fmaxf(0.f, fmaf(dy * rs, g.y, bb.y));
        if (LAST) {
            int gg = batch[n];  // wave-uniform
            if (gg != cur_g) {
                if (cur_g >= 0) {
                    atomicAdd(&pooled[cur_g * HDIM + c0],     accP.x);
                    atomicAdd(&pooled[cur_g * HDIM + c0 + 1], accP.y);
                }
                accP.x = 0.f; accP.y = 0.f;
                cur_g = gg;
            }
            accP.x += o.x; accP.y += o.y;
        } else {
            *(float2*)(h + (size_t)n * HDIM + c0) = o;
            float cs = c_src[n], cd = c_dst[n];
            accS.x = fmaf(cs, o.x, accS.x); accS.y = fmaf(cs, o.y, accS.y);
            accD.x = fmaf(cd, o.x, accD.x); accD.y = fmaf(cd, o.y, accD.y);
        }
    }
    if (LAST) {
        if (cur_g >= 0) {
            atomicAdd(&pooled[cur_g * HDIM + c0],     accP.x);
            atomicAdd(&pooled[cur_g * HDIM + c0 + 1], accP.y);
        }
    } else {
        __shared__ float sb[HDIM], db[HDIM];
        if (t < HDIM) { sb[t] = 0.f; db[t] = 0.f; }
        __syncthreads();
        atomicAdd(&sb[c0], accS.x); atomicAdd(&sb[c0 + 1], accS.y);
        atomicAdd(&db[c0], accD.x); atomicAdd(&db[c0 + 1], accD.y);
        __syncthreads();
        float* row = partials + (size_t)blockIdx.x * 512;
        if (t < 128) {
            row[t] = sb[t];        row[t + 128] = 0.f;
            row[t + 256] = db[t];  row[t + 384] = 0.f;
        }
    }
}

// ---------------- K6: out = (pooled / max(cnt,1)) @ w_out + b_out ----------------
__global__ __launch_bounds__(128) void k_out(const float* __restrict__ pooled,
        const int* __restrict__ batch, const float* __restrict__ w_out,
        const float* __restrict__ b_out, float* __restrict__ out, int N) {
    int gph = blockIdx.x;
    int t = threadIdx.x;
    __shared__ float p[HDIM];
    __shared__ int cntS;
    if (t == 0) {
        int lo = 0, hi = N;  // first idx with batch >= g  (batch is sorted)
        while (lo < hi) { int mid = (lo + hi) >> 1; if (batch[mid] < gph) lo = mid + 1; else hi = mid; }
        int lo2 = lo, hi2 = N;  // first idx with batch > g
        while (lo2 < hi2) { int mid = (lo2 + hi2) >> 1; if (batch[mid] <= gph) lo2 = mid + 1; else hi2 = mid; }
        cntS = lo2 - lo;
    }
    __syncthreads();
    float inv = 1.0f / fmaxf((float)cntS, 1.0f);
    p[t] = pooled[gph * HDIM + t] * inv;
    __syncthreads();
    float acc = b_out[t];
#pragma unroll 8
    for (int k = 0; k < HDIM; ++k) acc = fmaf(p[k], w_out[k * HDIM + t], acc);
    out[gph * HDIM + t] = acc;
}

extern "C" void kernel_launch(void* const* d_in, const int* in_sizes, int n_in,
                              void* d_out, int out_size, void* d_ws, size_t ws_size,
                              hipStream_t stream) {
    const float* x      = (const float*)d_in[0];
    const int*   ei     = (const int*)d_in[1];
    const float* ea     = (const float*)d_in[2];
    const int*   batch  = (const int*)d_in[3];
    const float* w_node = (const float*)d_in[4];
    const float* b_node = (const float*)d_in[5];
    const float* w_edge = (const float*)d_in[6];
    const float* b_edge = (const float*)d_in[7];
    const float* mp_w   = (const float*)d_in[8];
    const float* mp_b   = (const float*)d_in[9];
    const float* ln_g   = (const float*)d_in[10];
    const float* ln_b   = (const float*)d_in[11];
    const float* w_out  = (const float*)d_in[12];
    const float* b_out  = (const float*)d_in[13];
    float* out = (float*)d_out;
    int N = in_sizes[3];
    int E = in_sizes[2] / EDIM;

    float* ws = (float*)d_ws;
    size_t off = 0;
    float* h        = ws + off; off += (size_t)N * HDIM;
    float* c_src    = ws + off; off += N;
    float* c_dst    = ws + off; off += N;
    float* sum_attr = ws + off; off += 8;
    float* pooled   = ws + off; off += NGRAPHS * HDIM;
    float* s_cat_g  = ws + off; off += 512;
    float* mean_msg = ws + off; off += 128;
    float* partials = ws + off; off += (size_t)1024 * 512;

    // zero the accumulators: c_src, c_dst, sum_attr, pooled, s_cat_g (contiguous)
    size_t zero_count = (size_t)2 * N + 8 + NGRAPHS * HDIM + 512;
    hipMemsetAsync(c_src, 0, zero_count * sizeof(float), stream);

    k_hist<<<(E + 255) / 256, 256, 0, stream>>>(ei, c_src, c_dst, E);
    k_edgesum<<<128, 256, 0, stream>>>(ea, sum_attr, E);

    const int NB3 = 512;
    k_node<<<NB3, 256, 0, stream>>>(x, w_node, b_node, c_src, c_dst, h, partials, N);

    const int NB5 = 1024;
    int cpb = (N + NB5 - 1) / NB5;
    int nb = NB3;
    for (int i = 0; i < 3; ++i) {
        k_red<<<(nb + 31) / 32, 256, 0, stream>>>(partials, s_cat_g, nb);
        k_mm<<<1, 256, 0, stream>>>(s_cat_g, sum_attr, w_edge, b_edge,
                                    mp_w + (size_t)i * 384 * HDIM,
                                    mp_b + (size_t)i * HDIM, mean_msg, E);
        if (i < 2) {
            k_update<0><<<NB5, 256, 0, stream>>>(h, mean_msg, ln_g, ln_b, c_src, c_dst,
                                                 batch, partials, pooled, N, cpb);
            nb = NB5;
        } else {
            k_update<1><<<NB5, 256, 0, stream>>>(h, mean_msg, ln_g, ln_b, c_src, c_dst,
                                                 batch, partials, pooled, N, cpb);
        }
    }
    k_out<<<NGRAPHS, HDIM, 0, stream>>>(pooled, batch, w_out, b_out, out, N);
}